// Round 4
// baseline (376.300 us; speedup 1.0000x reference)
//
#include <hip/hip_runtime.h>
#include <math.h>

#define C_IN  512
#define C_OUT 4
#define WDIM  128
#define HW    16384   // 128*128 pixels per image
#define BATCH 8

// ---------------- Kernel 1: per-image effective 1x1 kernel ----------------
// ke[b][c] (float4 over outputs) = ((w[b]·affine_w[:,c] + affine_b[c]) / sqrt(512)) * k2d[c][:]
__global__ __launch_bounds__(128) void ke_kernel(
    const float* __restrict__ w, const float* __restrict__ aw,
    const float* __restrict__ ab, const float* __restrict__ k2d,
    float* __restrict__ ke)
{
    const int b = blockIdx.x >> 2;
    const int c = ((blockIdx.x & 3) << 7) | threadIdx.x;
    const float* __restrict__ wr = w + b * WDIM;   // wave-uniform row
    float s = 0.f;
    #pragma unroll 8
    for (int j = 0; j < WDIM; ++j)
        s = fmaf(wr[j], aw[j * C_IN + c], s);       // coalesced across lanes
    s = (s + ab[c]) * 0.04419417382415922f;         // 1/sqrt(512)
    const float4 kk = ((const float4*)k2d)[c];
    float4 o;
    o.x = s * kk.x; o.y = s * kk.y; o.z = s * kk.z; o.w = s * kk.w;
    ((float4*)ke)[b * C_IN + c] = o;
}

// ds_swizzle pattern must be a compile-time constant -> template parameter.
template <int PATTERN>
__device__ __forceinline__ float swz(float v) {
    return __int_as_float(__builtin_amdgcn_ds_swizzle(__float_as_int(v), PATTERN));
}

__device__ __forceinline__ float fast_tanh(float x) {
    // tanh(x) = 1 - 2/(e^{2x}+1); ~1e-6 rel error (threshold 2e-2)
    float e = __expf(2.0f * x);
    return 1.0f - 2.0f / (e + 1.0f);
}

// ---------------- Kernel 2: wave-per-pixel, split-K over lanes ----------------
// Lane l owns channels [4l..4l+3] and [256+4l..256+4l+3]; both x float4 loads
// per pixel are perfectly coalesced 1 KiB wave transactions; each lane keeps
// its 8 ke rows (32 VGPRs) for the whole kernel.
//
// Reduction: merged multi-accumulator butterfly. Two select-merge stages fold
// a0..a3 into ONE value per lane (lane l carries accumulator l&3, summed over
// its 4-lane group), then plain xor4/xor8/xor16/xor32 butterflies. Lanes 0..3
// end with the full sums for channels 0..3 and store one dword each.
__global__ __launch_bounds__(256) void torgb_kernel(
    const float* __restrict__ x, const float* __restrict__ ke,
    const float* __restrict__ bias, float* __restrict__ out)
{
    const int lane   = threadIdx.x & 63;
    const int wave_g = (blockIdx.x << 2) | (threadIdx.x >> 6);   // 4 waves/block
    const int pix_base = wave_g * 16;                            // 16 px per wave
    const int b = pix_base >> 14;                                // uniform per wave

    const float4* __restrict__ kp = (const float4*)ke + (size_t)b * C_IN;
    float4 kr0[4], kr1[4];
    #pragma unroll
    for (int j = 0; j < 4; ++j) {
        kr0[j] = kp[4 * lane + j];          // channels 4l..4l+3
        kr1[j] = kp[256 + 4 * lane + j];    // channels 256+4l..256+4l+3
    }
    const float4 bb = *(const float4*)bias;
    // per-lane bias for channel (lane&3)
    float bsel  = (lane & 1) ? bb.y : bb.x;
    float bsel2 = (lane & 1) ? bb.w : bb.z;
    bsel = (lane & 2) ? bsel2 : bsel;

    #pragma unroll 2
    for (int i = 0; i < 16; ++i) {
        const int pix = pix_base + i;
        const float4* __restrict__ xp = (const float4*)(x + (size_t)pix * C_IN);
        const float4 xa = xp[lane];        // coalesced 1 KiB wave load
        const float4 xb = xp[64 + lane];   // second KiB of the row

        float a0 = 0.f, a1 = 0.f, a2 = 0.f, a3 = 0.f;
        a0 = fmaf(xa.x, kr0[0].x, fmaf(xa.y, kr0[1].x, fmaf(xa.z, kr0[2].x, fmaf(xa.w, kr0[3].x, a0))));
        a1 = fmaf(xa.x, kr0[0].y, fmaf(xa.y, kr0[1].y, fmaf(xa.z, kr0[2].y, fmaf(xa.w, kr0[3].y, a1))));
        a2 = fmaf(xa.x, kr0[0].z, fmaf(xa.y, kr0[1].z, fmaf(xa.z, kr0[2].z, fmaf(xa.w, kr0[3].z, a2))));
        a3 = fmaf(xa.x, kr0[0].w, fmaf(xa.y, kr0[1].w, fmaf(xa.z, kr0[2].w, fmaf(xa.w, kr0[3].w, a3))));
        a0 = fmaf(xb.x, kr1[0].x, fmaf(xb.y, kr1[1].x, fmaf(xb.z, kr1[2].x, fmaf(xb.w, kr1[3].x, a0))));
        a1 = fmaf(xb.x, kr1[0].y, fmaf(xb.y, kr1[1].y, fmaf(xb.z, kr1[2].y, fmaf(xb.w, kr1[3].y, a1))));
        a2 = fmaf(xb.x, kr1[0].z, fmaf(xb.y, kr1[1].z, fmaf(xb.z, kr1[2].z, fmaf(xb.w, kr1[3].z, a2))));
        a3 = fmaf(xb.x, kr1[0].w, fmaf(xb.y, kr1[1].w, fmaf(xb.z, kr1[2].w, fmaf(xb.w, kr1[3].w, a3))));

        // --- merge stage A (xor1, swizzle 0x041F): fold {a0,a1} and {a2,a3}
        float s01 = (lane & 1) ? a0 : a1;            // what my partner needs
        float s23 = (lane & 1) ? a2 : a3;
        float m01 = ((lane & 1) ? a1 : a0) + swz<0x041F>(s01);
        float m23 = ((lane & 1) ? a3 : a2) + swz<0x041F>(s23);
        // --- merge stage B (xor2, 0x081F): lane ends with accumulator (lane&3)
        float sB = (lane & 2) ? m01 : m23;
        float m  = ((lane & 2) ? m23 : m01) + swz<0x081F>(sB);
        // --- plain butterflies: xor4, xor8, xor16, xor32
        m += swz<0x101F>(m);
        m += swz<0x201F>(m);
        m += swz<0x401F>(m);
        m += __shfl_xor(m, 32, 64);

        const float r = fast_tanh(m + bsel);
        if (lane < 4)
            out[(size_t)pix * C_OUT + lane] = r;     // 4 contiguous dwords
    }
}

extern "C" void kernel_launch(void* const* d_in, const int* in_sizes, int n_in,
                              void* d_out, int out_size, void* d_ws, size_t ws_size,
                              hipStream_t stream) {
    const float* x    = (const float*)d_in[0];   // [8,128,128,512]
    const float* w    = (const float*)d_in[1];   // [8,128]
    const float* aw   = (const float*)d_in[2];   // [128,512]
    const float* ab   = (const float*)d_in[3];   // [512]
    const float* kk   = (const float*)d_in[4];   // [1,1,512,4]
    const float* bias = (const float*)d_in[5];   // [4]
    float* out = (float*)d_out;                  // [8,128,128,4] fp32
    float* ke  = (float*)d_ws;                   // 8*512*4 floats = 64 KB scratch

    hipLaunchKernelGGL(ke_kernel, dim3(BATCH * 4), dim3(128), 0, stream,
                       w, aw, ab, kk, ke);
    // 131072 pixels / (16 px/wave * 4 waves/block) = 2048 blocks
    hipLaunchKernelGGL(torgb_kernel, dim3(2048), dim3(256), 0, stream,
                       x, ke, bias, out);
}